// Round 5
// baseline (30458.786 us; speedup 1.0000x reference)
//
#include <hip/hip_runtime.h>
#include <hip/hip_bf16.h>
#include <stdint.h>

// Problem dims
#define BATCH 256
#define SEQ   512
#define INDIM 64
#define H     128
#define RB    4               // batch rows per block (valid C-rows at quad*4, r=0)
#define NTILE (BATCH / RB)    // 64 batch tiles per layer
#define CH    16              // pipeline handoff chunk (steps)
#define NCH   (SEQ / CH)

using short8  = __attribute__((ext_vector_type(8))) short;  // 8 bf16 MFMA A/B frag
using float4v = __attribute__((ext_vector_type(4))) float;  // MFMA C/D frag

#define LOG2E 1.4426950408889634f

__device__ __forceinline__ unsigned short f2bf(float f) {
    union { float f; uint32_t u; } v; v.f = f;
    uint32_t u = v.u;
    return (unsigned short)((u + 0x7FFFu + ((u >> 16) & 1u)) >> 16); // RNE
}

__device__ __forceinline__ float fast_exp2(float x) {
#if __has_builtin(__builtin_amdgcn_exp2f)
    return __builtin_amdgcn_exp2f(x);
#else
    return __expf(x * 0.6931471805599453f);
#endif
}
__device__ __forceinline__ float fast_rcp(float x) {
#if __has_builtin(__builtin_amdgcn_rcpf)
    return __builtin_amdgcn_rcpf(x);
#else
    return 1.f / x;
#endif
}
__device__ __forceinline__ float sigmoid_fast(float x) {
    return fast_rcp(1.f + fast_exp2(-LOG2E * x));
}
__device__ __forceinline__ float tanh_fast(float x) {
    return fmaf(-2.f, fast_rcp(1.f + fast_exp2((2.f * LOG2E) * x)), 1.f);
}

// In-chunk per-step barrier: LDS ordering only (lgkmcnt). Global prefetch
// loads and producer h-stores stay in flight across it (waited at use /
// chunk end). Full __syncthreads (vmcnt drain) only at chunk boundaries.
__device__ __forceinline__ void light_barrier() {
    asm volatile("s_waitcnt lgkmcnt(0)\n\ts_barrier" ::: "memory");
}

// ---------------- x fp32 -> bf16 convert (+ flag zeroing) ----------------
__global__ void conv_x_kernel(const float* __restrict__ x,
                              unsigned short* __restrict__ xb, int n4,
                              int* __restrict__ flags) {
    int i = blockIdx.x * blockDim.x + threadIdx.x;
    if (blockIdx.x == 0 && threadIdx.x < NTILE) flags[threadIdx.x] = 0;
    if (i >= n4) return;
    float4 f = ((const float4*)x)[i];
    ushort4 o;
    o.x = f2bf(f.x); o.y = f2bf(f.y); o.z = f2bf(f.z); o.w = f2bf(f.w);
    ((ushort4*)xb)[i] = o;
}

// ---------------- fused 2-layer pipelined LSTM + head ----------------
// 128 blocks x 512 threads. Blocks 0..63: layer0 (producer), 64..127: layer1
// (consumer), paired on batch tile bt (same XCD: 64%8==0). RB=4 batch rows at
// MFMA C-rows {0,4,8,12} -> every lane does exactly one cell update.
// Software pipeline: the x-projection MFMAs for step t+1 run BEFORE the step
// barrier (they don't depend on h(t)), overlapping the activation chain; the
// post-barrier critical path is ds_read h -> 4 dependent h-MFMAs -> extract
// -> activation -> ds_write. x regs are a 2-ring with prefetch distance 2.
template<int KIN, bool IS_PROD>
__device__ __forceinline__ void lstm_body(
    const unsigned short* __restrict__ xin,  // [BATCH][SEQ][KIN] bf16
    const float* __restrict__ Wih,           // [4H][KIN]
    const float* __restrict__ Whh,           // [4H][H]
    const float* __restrict__ b_ih, const float* __restrict__ b_hh,
    unsigned short* __restrict__ outseq,     // producer: [BATCH][SEQ][H] bf16
    const float* __restrict__ W1, const float* __restrict__ b1,
    const float* __restrict__ W2, const float* __restrict__ b2,
    float* __restrict__ out,                 // consumer: [BATCH][3]
    int* flag, int bt)
{
    constexpr int KT  = KIN / 32;
    constexpr int PAD = 132;                 // 66 dwords == 2 mod 32 -> 2-way (free) aliasing
    const int lane = threadIdx.x & 63;
    const int quad = lane >> 4;
    const int l16  = lane & 15;
    const int b0   = bt * RB;
    const int cell = (threadIdx.x >> 6) * 16 + l16;
    const int arow = l16 & 12;               // LDS h row this lane reads (4-lane broadcast)
    const int xrow = b0 + (l16 >> 2);        // batch row this lane loads (duplicated 4x)

    __shared__ short hbuf[2][16][PAD];
    __shared__ float hl[RB][128];            // fp32 h_last (consumer head input)
    __shared__ float mid[RB][65];
    for (int i = threadIdx.x; i < 2 * 16 * PAD; i += 512) ((short*)hbuf)[i] = 0;

    // ---- weight fragments (loaded once, fp32->bf16, persist in registers) ----
    short8 whh_f[4][4];
    short8 wih_f[4][KT];
    float  bias[4];
#pragma unroll
    for (int tT = 0; tT < 4; tT++) {
        const int n = tT * 128 + cell;
#pragma unroll
        for (int kt = 0; kt < 4; kt++) {
            const float* p = Whh + (size_t)n * H + kt * 32 + quad * 8;
            float4 f0 = *(const float4*)p;
            float4 f1 = *(const float4*)(p + 4);
            short8 s;
            s[0]=f2bf(f0.x); s[1]=f2bf(f0.y); s[2]=f2bf(f0.z); s[3]=f2bf(f0.w);
            s[4]=f2bf(f1.x); s[5]=f2bf(f1.y); s[6]=f2bf(f1.z); s[7]=f2bf(f1.w);
            whh_f[tT][kt] = s;
        }
#pragma unroll
        for (int kt = 0; kt < KT; kt++) {
            const float* p = Wih + (size_t)n * KIN + kt * 32 + quad * 8;
            float4 f0 = *(const float4*)p;
            float4 f1 = *(const float4*)(p + 4);
            short8 s;
            s[0]=f2bf(f0.x); s[1]=f2bf(f0.y); s[2]=f2bf(f0.z); s[3]=f2bf(f0.w);
            s[4]=f2bf(f1.x); s[5]=f2bf(f1.y); s[6]=f2bf(f1.z); s[7]=f2bf(f1.w);
            wih_f[tT][kt] = s;
        }
        bias[tT] = b_ih[n] + b_hh[n];
    }

    float c0 = 0.f;                          // this lane's single cell state

    const unsigned short* xp = xin + ((size_t)xrow * SEQ) * KIN + quad * 8;
    unsigned short* op = nullptr;
    if (IS_PROD)
        op = outseq + ((size_t)(b0 + quad) * SEQ) * H + cell;

    short8  xf[2][KT];                       // x reg ring: xf[t&1] ~ x(t)
    float4v acc[4];                          // carries bias + x-partial into each step
    __syncthreads();                         // hbuf zero-init visible

    for (int ch = 0; ch < NCH; ch++) {
        const int t0 = ch * CH;              // (CH even -> t0&1 == 0)
        if (!IS_PROD) {
            if (threadIdx.x == 0) {
                while (__hip_atomic_load(flag, __ATOMIC_RELAXED, __HIP_MEMORY_SCOPE_AGENT) <= ch)
                    __builtin_amdgcn_s_sleep(2);
                (void)__hip_atomic_load(flag, __ATOMIC_ACQUIRE, __HIP_MEMORY_SCOPE_AGENT);
            }
            __syncthreads();
        }
        // chunk start: load x(t0), x(t0+1); compute bias + x-partial for t0
        {
            const unsigned short* p0 = xp + (size_t)t0 * KIN;
            const unsigned short* p1 = p0 + KIN;
#pragma unroll
            for (int kt = 0; kt < KT; kt++) {
                xf[0][kt] = *(const short8*)(p0 + kt * 32);
                xf[1][kt] = *(const short8*)(p1 + kt * 32);
            }
        }
#pragma unroll
        for (int tT = 0; tT < 4; tT++)
            acc[tT] = (float4v){bias[tT], bias[tT], bias[tT], bias[tT]};
#pragma unroll
        for (int tT = 0; tT < 4; tT++)
#pragma unroll
            for (int kt = 0; kt < KT; kt++)
                acc[tT] = __builtin_amdgcn_mfma_f32_16x16x32_bf16(xf[0][kt], wih_f[tT][kt], acc[tT], 0, 0, 0);

#pragma unroll 1
        for (int i = 0; i < CH; i++) {
            const int t   = t0 + i;
            const int cur = t & 1;
            // ---- post-barrier critical path: h-MFMAs on acc (x-part already in)
            short8 ha[4];
#pragma unroll
            for (int kt = 0; kt < 4; kt++)
                ha[kt] = *(const short8*)&hbuf[cur][arow][kt * 32 + quad * 8];
#pragma unroll
            for (int tT = 0; tT < 4; tT++)
#pragma unroll
                for (int kt = 0; kt < 4; kt++)
                    acc[tT] = __builtin_amdgcn_mfma_f32_16x16x32_bf16(ha[kt], whh_f[tT][kt], acc[tT], 0, 0, 0);
            // extract this lane's 4 gate scalars (C-row quad*4, r=0)
            float g0 = acc[0][0], g1 = acc[1][0], g2 = acc[2][0], g3 = acc[3][0];

            // ---- off-path work while activation chain runs:
            // prefetch x(t+2) into the dead ring slot
            const bool doPre = IS_PROD ? (t + 2 < SEQ) : (i + 2 < CH);
            if (doPre) {
                const unsigned short* p = xp + (size_t)(t + 2) * KIN;
#pragma unroll
                for (int kt = 0; kt < KT; kt++) xf[cur][kt] = *(const short8*)(p + kt * 32);
            }
            // bias + x-partial for t+1 (skip at chunk end; recomputed at chunk start)
            if (i < CH - 1) {
#pragma unroll
                for (int tT = 0; tT < 4; tT++)
                    acc[tT] = (float4v){bias[tT], bias[tT], bias[tT], bias[tT]};
#pragma unroll
                for (int tT = 0; tT < 4; tT++)
#pragma unroll
                    for (int kt = 0; kt < KT; kt++)
                        acc[tT] = __builtin_amdgcn_mfma_f32_16x16x32_bf16(xf[cur ^ 1][kt], wih_f[tT][kt], acc[tT], 0, 0, 0);
            }

            // ---- activation + h publish
            float si = sigmoid_fast(g0);
            float sf = sigmoid_fast(g1);
            float tg = tanh_fast(g2);
            float so = sigmoid_fast(g3);
            float cn = fmaf(sf, c0, si * tg);
            c0 = cn;
            float h = so * tanh_fast(cn);
            const unsigned short hb = f2bf(h);
            hbuf[cur ^ 1][quad * 4][cell] = (short)hb;
            if (IS_PROD) {
                *op = hb;                    // fire-and-forget; drained at chunk end
                op += H;
            } else if (t == SEQ - 1) {
                hl[quad][cell] = h;
            }
            light_barrier();                 // LDS-only: loads/stores stay in flight
        }
        __syncthreads();                     // vmcnt drain (producer stores) + boundary
        if (IS_PROD && threadIdx.x == 0)
            __hip_atomic_fetch_add(flag, 1, __ATOMIC_RELEASE, __HIP_MEMORY_SCOPE_AGENT);
    }

    if (!IS_PROD) {
        // ---- MLP head for this block's RB rows (hl visible via last barrier)
        if (threadIdx.x < RB * 64) {
            const int row = threadIdx.x >> 6, j = threadIdx.x & 63;
            float s = b1[j];
            const float* wr = W1 + (size_t)j * 128;
#pragma unroll 8
            for (int k = 0; k < 128; k++) s = fmaf(hl[row][k], wr[k], s);
            mid[row][j] = fmaxf(s, 0.f);
        }
        __syncthreads();
        if (threadIdx.x < RB * 3) {
            const int row = threadIdx.x / 3, k = threadIdx.x - row * 3;
            float o = b2[k];
            const float* wr = W2 + (size_t)k * 64;
#pragma unroll 8
            for (int j = 0; j < 64; j++) o = fmaf(mid[row][j], wr[j], o);
            out[(size_t)(b0 + row) * 3 + k] = o;
        }
    }
}

__global__ __launch_bounds__(512, 2)
void lstm_fused_kernel(const unsigned short* __restrict__ xb,
                       const float* __restrict__ Wih0, const float* __restrict__ Whh0,
                       const float* __restrict__ bih0, const float* __restrict__ bhh0,
                       const float* __restrict__ Wih1, const float* __restrict__ Whh1,
                       const float* __restrict__ bih1, const float* __restrict__ bhh1,
                       unsigned short* __restrict__ h0sq,
                       const float* __restrict__ W1, const float* __restrict__ b1,
                       const float* __restrict__ W2, const float* __restrict__ b2,
                       float* __restrict__ out,
                       int* __restrict__ flags)
{
    const int bt = blockIdx.x & (NTILE - 1);
    if (blockIdx.x < NTILE)
        lstm_body<64,  true >(xb,   Wih0, Whh0, bih0, bhh0, h0sq,
                              W1, b1, W2, b2, out, flags + bt, bt);
    else
        lstm_body<128, false>(h0sq, Wih1, Whh1, bih1, bhh1, nullptr,
                              W1, b1, W2, b2, out, flags + bt, bt);
}

extern "C" void kernel_launch(void* const* d_in, const int* in_sizes, int n_in,
                              void* d_out, int out_size, void* d_ws, size_t ws_size,
                              hipStream_t stream) {
    const float* x     = (const float*)d_in[0];
    const float* W_ih0 = (const float*)d_in[1];
    const float* W_hh0 = (const float*)d_in[2];
    const float* b_ih0 = (const float*)d_in[3];
    const float* b_hh0 = (const float*)d_in[4];
    const float* W_ih1 = (const float*)d_in[5];
    const float* W_hh1 = (const float*)d_in[6];
    const float* b_ih1 = (const float*)d_in[7];
    const float* b_hh1 = (const float*)d_in[8];
    const float* W1    = (const float*)d_in[9];
    const float* b1    = (const float*)d_in[10];
    const float* W2    = (const float*)d_in[11];
    const float* b2    = (const float*)d_in[12];
    float* out = (float*)d_out;

    // workspace: xb bf16[256*512*64] @0 (16 MB); h0sq bf16[256*512*128] @16 MB (32 MB); flags @48 MB
    char* ws = (char*)d_ws;
    unsigned short* xb    = (unsigned short*)ws;
    unsigned short* h0sq  = (unsigned short*)(ws + 16777216);
    int*            flags = (int*)(ws + 50331648);

    conv_x_kernel<<<8192, 256, 0, stream>>>(x, xb, (BATCH * SEQ * INDIM) / 4, flags);
    lstm_fused_kernel<<<2 * NTILE, 512, 0, stream>>>(xb, W_ih0, W_hh0, b_ih0, b_hh0,
                                                     W_ih1, W_hh1, b_ih1, b_hh1,
                                                     h0sq, W1, b1, W2, b2, out, flags);
}

// Round 6
// 30402.393 us; speedup vs baseline: 1.0019x; 1.0019x over previous
//
#include <hip/hip_runtime.h>
#include <hip/hip_bf16.h>
#include <stdint.h>

// Problem dims
#define BATCH 256
#define SEQ   512
#define INDIM 64
#define H     128
#define RB    4               // batch rows per block (valid C-rows at quad*4, r=0)
#define NTILE (BATCH / RB)    // 64 batch tiles per layer
#define CH    16              // pipeline handoff chunk (steps)
#define NCH   (SEQ / CH)

using short8  = __attribute__((ext_vector_type(8))) short;  // 8 bf16 MFMA A/B frag
using float4v = __attribute__((ext_vector_type(4))) float;  // MFMA C/D frag

#define LOG2E 1.4426950408889634f

__device__ __forceinline__ unsigned short f2bf(float f) {
    union { float f; uint32_t u; } v; v.f = f;
    uint32_t u = v.u;
    return (unsigned short)((u + 0x7FFFu + ((u >> 16) & 1u)) >> 16); // RNE
}

__device__ __forceinline__ float fast_exp2(float x) {
#if __has_builtin(__builtin_amdgcn_exp2f)
    return __builtin_amdgcn_exp2f(x);
#else
    return __expf(x * 0.6931471805599453f);
#endif
}
__device__ __forceinline__ float fast_rcp(float x) {
#if __has_builtin(__builtin_amdgcn_rcpf)
    return __builtin_amdgcn_rcpf(x);
#else
    return 1.f / x;
#endif
}
__device__ __forceinline__ float sigmoid_fast(float x) {
    return fast_rcp(1.f + fast_exp2(-LOG2E * x));
}
__device__ __forceinline__ float tanh_fast(float x) {
    return fmaf(-2.f, fast_rcp(1.f + fast_exp2((2.f * LOG2E) * x)), 1.f);
}

// In-chunk per-step barrier: LDS ordering only (lgkmcnt). Global prefetch
// loads and producer h-stores stay in flight across it. Full __syncthreads
// (vmcnt drain) only at chunk boundaries.
__device__ __forceinline__ void light_barrier() {
    asm volatile("s_waitcnt lgkmcnt(0)\n\ts_barrier" ::: "memory");
}

// ---------------- x fp32 -> bf16 convert (+ flag zeroing) ----------------
__global__ void conv_x_kernel(const float* __restrict__ x,
                              unsigned short* __restrict__ xb, int n4,
                              int* __restrict__ flags) {
    int i = blockIdx.x * blockDim.x + threadIdx.x;
    if (blockIdx.x == 0 && threadIdx.x < NTILE) flags[threadIdx.x] = 0;
    if (i >= n4) return;
    float4 f = ((const float4*)x)[i];
    ushort4 o;
    o.x = f2bf(f.x); o.y = f2bf(f.y); o.z = f2bf(f.z); o.w = f2bf(f.w);
    ((ushort4*)xb)[i] = o;
}

// ---------------- fused 2-layer pipelined LSTM + head ----------------
// 128 blocks x 512 threads. Blocks 0..63: layer0 (producer), 64..127: layer1
// (consumer), paired on batch tile bt. RB=4 batch rows at MFMA C-rows
// {0,4,8,12} -> every lane does exactly one cell update. x-projection MFMAs
// for step t+1 run BEFORE the step barrier (independent of h(t)), overlapping
// the activation chain. Weights persist in VGPRs: live set ~210 VGPRs, so the
// wave MUST get a 256-VGPR budget — amdgpu_waves_per_eu(2,2) pins exactly
// 2 waves/SIMD (the 8-wave block's natural occupancy) and stops the allocator
// from squeezing to 128 VGPRs (which forced per-step weight remat in R2-R4
// and scratch spills in R5).
template<int KIN, bool IS_PROD>
__device__ __forceinline__ void lstm_body(
    const unsigned short* __restrict__ xin,  // [BATCH][SEQ][KIN] bf16
    const float* __restrict__ Wih,           // [4H][KIN]
    const float* __restrict__ Whh,           // [4H][H]
    const float* __restrict__ b_ih, const float* __restrict__ b_hh,
    unsigned short* __restrict__ outseq,     // producer: [BATCH][SEQ][H] bf16
    const float* __restrict__ W1, const float* __restrict__ b1,
    const float* __restrict__ W2, const float* __restrict__ b2,
    float* __restrict__ out,                 // consumer: [BATCH][3]
    int* flag, int bt)
{
    constexpr int KT  = KIN / 32;
    constexpr int PAD = 132;                 // 66 dwords == 2 mod 32 -> 2-way (free) aliasing
    const int lane = threadIdx.x & 63;
    const int quad = lane >> 4;
    const int l16  = lane & 15;
    const int b0   = bt * RB;
    const int cell = (threadIdx.x >> 6) * 16 + l16;
    const int arow = l16 & 12;               // LDS h row this lane reads (4-lane broadcast)
    const int xrow = b0 + (l16 >> 2);        // batch row this lane loads (duplicated 4x)

    __shared__ short hbuf[2][16][PAD];
    __shared__ float hl[RB][128];            // fp32 h_last (consumer head input)
    __shared__ float mid[RB][65];
    for (int i = threadIdx.x; i < 2 * 16 * PAD; i += 512) ((short*)hbuf)[i] = 0;

    // ---- weight fragments (loaded once, fp32->bf16, persist in registers) ----
    short8 whh_f[4][4];
    short8 wih_f[4][KT];
    float  bias[4];
#pragma unroll
    for (int tT = 0; tT < 4; tT++) {
        const int n = tT * 128 + cell;
#pragma unroll
        for (int kt = 0; kt < 4; kt++) {
            const float* p = Whh + (size_t)n * H + kt * 32 + quad * 8;
            float4 f0 = *(const float4*)p;
            float4 f1 = *(const float4*)(p + 4);
            short8 s;
            s[0]=f2bf(f0.x); s[1]=f2bf(f0.y); s[2]=f2bf(f0.z); s[3]=f2bf(f0.w);
            s[4]=f2bf(f1.x); s[5]=f2bf(f1.y); s[6]=f2bf(f1.z); s[7]=f2bf(f1.w);
            whh_f[tT][kt] = s;
        }
#pragma unroll
        for (int kt = 0; kt < KT; kt++) {
            const float* p = Wih + (size_t)n * KIN + kt * 32 + quad * 8;
            float4 f0 = *(const float4*)p;
            float4 f1 = *(const float4*)(p + 4);
            short8 s;
            s[0]=f2bf(f0.x); s[1]=f2bf(f0.y); s[2]=f2bf(f0.z); s[3]=f2bf(f0.w);
            s[4]=f2bf(f1.x); s[5]=f2bf(f1.y); s[6]=f2bf(f1.z); s[7]=f2bf(f1.w);
            wih_f[tT][kt] = s;
        }
        bias[tT] = b_ih[n] + b_hh[n];
    }

    float c0 = 0.f;                          // this lane's single cell state

    const unsigned short* xp = xin + ((size_t)xrow * SEQ) * KIN + quad * 8;
    unsigned short* op = nullptr;
    if (IS_PROD)
        op = outseq + ((size_t)(b0 + quad) * SEQ) * H + cell;

    short8  xf[2][KT];                       // x reg ring: xf[t&1] ~ x(t)
    float4v acc[4];                          // carries bias + x-partial into each step
    __syncthreads();                         // hbuf zero-init visible

    for (int ch = 0; ch < NCH; ch++) {
        const int t0 = ch * CH;              // (CH even -> t0&1 == 0)
        if (!IS_PROD) {
            if (threadIdx.x == 0) {
                while (__hip_atomic_load(flag, __ATOMIC_RELAXED, __HIP_MEMORY_SCOPE_AGENT) <= ch)
                    __builtin_amdgcn_s_sleep(2);
                (void)__hip_atomic_load(flag, __ATOMIC_ACQUIRE, __HIP_MEMORY_SCOPE_AGENT);
            }
            __syncthreads();
        }
        // chunk start: load x(t0), x(t0+1); compute bias + x-partial for t0
        {
            const unsigned short* p0 = xp + (size_t)t0 * KIN;
            const unsigned short* p1 = p0 + KIN;
#pragma unroll
            for (int kt = 0; kt < KT; kt++) {
                xf[0][kt] = *(const short8*)(p0 + kt * 32);
                xf[1][kt] = *(const short8*)(p1 + kt * 32);
            }
        }
#pragma unroll
        for (int tT = 0; tT < 4; tT++)
            acc[tT] = (float4v){bias[tT], bias[tT], bias[tT], bias[tT]};
#pragma unroll
        for (int tT = 0; tT < 4; tT++)
#pragma unroll
            for (int kt = 0; kt < KT; kt++)
                acc[tT] = __builtin_amdgcn_mfma_f32_16x16x32_bf16(xf[0][kt], wih_f[tT][kt], acc[tT], 0, 0, 0);

#pragma unroll 1
        for (int i = 0; i < CH; i++) {
            const int t   = t0 + i;
            const int cur = t & 1;
            // ---- post-barrier critical path: h-MFMAs on acc (x-part already in)
            short8 ha[4];
#pragma unroll
            for (int kt = 0; kt < 4; kt++)
                ha[kt] = *(const short8*)&hbuf[cur][arow][kt * 32 + quad * 8];
#pragma unroll
            for (int tT = 0; tT < 4; tT++)
#pragma unroll
                for (int kt = 0; kt < 4; kt++)
                    acc[tT] = __builtin_amdgcn_mfma_f32_16x16x32_bf16(ha[kt], whh_f[tT][kt], acc[tT], 0, 0, 0);
            // extract this lane's 4 gate scalars (C-row quad*4, r=0)
            float g0 = acc[0][0], g1 = acc[1][0], g2 = acc[2][0], g3 = acc[3][0];

            // ---- off-path work while activation chain runs:
            // prefetch x(t+2) into the dead ring slot
            const bool doPre = IS_PROD ? (t + 2 < SEQ) : (i + 2 < CH);
            if (doPre) {
                const unsigned short* p = xp + (size_t)(t + 2) * KIN;
#pragma unroll
                for (int kt = 0; kt < KT; kt++) xf[cur][kt] = *(const short8*)(p + kt * 32);
            }
            // bias + x-partial for t+1 (skip at chunk end; recomputed at chunk start)
            if (i < CH - 1) {
#pragma unroll
                for (int tT = 0; tT < 4; tT++)
                    acc[tT] = (float4v){bias[tT], bias[tT], bias[tT], bias[tT]};
#pragma unroll
                for (int tT = 0; tT < 4; tT++)
#pragma unroll
                    for (int kt = 0; kt < KT; kt++)
                        acc[tT] = __builtin_amdgcn_mfma_f32_16x16x32_bf16(xf[cur ^ 1][kt], wih_f[tT][kt], acc[tT], 0, 0, 0);
            }

            // ---- activation + h publish
            float si = sigmoid_fast(g0);
            float sf = sigmoid_fast(g1);
            float tg = tanh_fast(g2);
            float so = sigmoid_fast(g3);
            float cn = fmaf(sf, c0, si * tg);
            c0 = cn;
            float h = so * tanh_fast(cn);
            const unsigned short hb = f2bf(h);
            hbuf[cur ^ 1][quad * 4][cell] = (short)hb;
            if (IS_PROD) {
                *op = hb;                    // fire-and-forget; drained at chunk end
                op += H;
            } else if (t == SEQ - 1) {
                hl[quad][cell] = h;
            }
            light_barrier();                 // LDS-only: loads/stores stay in flight
        }
        __syncthreads();                     // vmcnt drain (producer stores) + boundary
        if (IS_PROD && threadIdx.x == 0)
            __hip_atomic_fetch_add(flag, 1, __ATOMIC_RELEASE, __HIP_MEMORY_SCOPE_AGENT);
    }

    if (!IS_PROD) {
        // ---- MLP head for this block's RB rows (hl visible via last barrier)
        if (threadIdx.x < RB * 64) {
            const int row = threadIdx.x >> 6, j = threadIdx.x & 63;
            float s = b1[j];
            const float* wr = W1 + (size_t)j * 128;
#pragma unroll 8
            for (int k = 0; k < 128; k++) s = fmaf(hl[row][k], wr[k], s);
            mid[row][j] = fmaxf(s, 0.f);
        }
        __syncthreads();
        if (threadIdx.x < RB * 3) {
            const int row = threadIdx.x / 3, k = threadIdx.x - row * 3;
            float o = b2[k];
            const float* wr = W2 + (size_t)k * 64;
#pragma unroll 8
            for (int j = 0; j < 64; j++) o = fmaf(mid[row][j], wr[j], o);
            out[(size_t)(b0 + row) * 3 + k] = o;
        }
    }
}

__global__ __launch_bounds__(512)
__attribute__((amdgpu_waves_per_eu(2, 2)))   // pin 2 waves/SIMD -> 256-VGPR budget
void lstm_fused_kernel(const unsigned short* __restrict__ xb,
                       const float* __restrict__ Wih0, const float* __restrict__ Whh0,
                       const float* __restrict__ bih0, const float* __restrict__ bhh0,
                       const float* __restrict__ Wih1, const float* __restrict__ Whh1,
                       const float* __restrict__ bih1, const float* __restrict__ bhh1,
                       unsigned short* __restrict__ h0sq,
                       const float* __restrict__ W1, const float* __restrict__ b1,
                       const float* __restrict__ W2, const float* __restrict__ b2,
                       float* __restrict__ out,
                       int* __restrict__ flags)
{
    const int bt = blockIdx.x & (NTILE - 1);
    if (blockIdx.x < NTILE)
        lstm_body<64,  true >(xb,   Wih0, Whh0, bih0, bhh0, h0sq,
                              W1, b1, W2, b2, out, flags + bt, bt);
    else
        lstm_body<128, false>(h0sq, Wih1, Whh1, bih1, bhh1, nullptr,
                              W1, b1, W2, b2, out, flags + bt, bt);
}

extern "C" void kernel_launch(void* const* d_in, const int* in_sizes, int n_in,
                              void* d_out, int out_size, void* d_ws, size_t ws_size,
                              hipStream_t stream) {
    const float* x     = (const float*)d_in[0];
    const float* W_ih0 = (const float*)d_in[1];
    const float* W_hh0 = (const float*)d_in[2];
    const float* b_ih0 = (const float*)d_in[3];
    const float* b_hh0 = (const float*)d_in[4];
    const float* W_ih1 = (const float*)d_in[5];
    const float* W_hh1 = (const float*)d_in[6];
    const float* b_ih1 = (const float*)d_in[7];
    const float* b_hh1 = (const float*)d_in[8];
    const float* W1    = (const float*)d_in[9];
    const float* b1    = (const float*)d_in[10];
    const float* W2    = (const float*)d_in[11];
    const float* b2    = (const float*)d_in[12];
    float* out = (float*)d_out;

    // workspace: xb bf16[256*512*64] @0 (16 MB); h0sq bf16[256*512*128] @16 MB (32 MB); flags @48 MB
    char* ws = (char*)d_ws;
    unsigned short* xb    = (unsigned short*)ws;
    unsigned short* h0sq  = (unsigned short*)(ws + 16777216);
    int*            flags = (int*)(ws + 50331648);

    conv_x_kernel<<<8192, 256, 0, stream>>>(x, xb, (BATCH * SEQ * INDIM) / 4, flags);
    lstm_fused_kernel<<<2 * NTILE, 512, 0, stream>>>(xb, W_ih0, W_hh0, b_ih0, b_hh0,
                                                     W_ih1, W_hh1, b_ih1, b_hh1,
                                                     h0sq, W1, b1, W2, b2, out, flags);
}

// Round 7
// 512.719 us; speedup vs baseline: 59.4064x; 59.2965x over previous
//
#include <hip/hip_runtime.h>
#include <hip/hip_bf16.h>
#include <stdint.h>

// Problem dims
#define BATCH 256
#define SEQ   512
#define INDIM 64
#define H     128
#define RB    4               // batch rows per block (valid C-rows at quad*4, r=0)
#define NTILE (BATCH / RB)    // 64 batch tiles per layer
#define CH    16              // pipeline handoff chunk (steps)
#define NCH   (SEQ / CH)

using short8  = __attribute__((ext_vector_type(8))) short;  // 8 bf16 MFMA A/B frag
using float4v = __attribute__((ext_vector_type(4))) float;  // MFMA C/D frag

#define LOG2E 1.4426950408889634f

__device__ __forceinline__ unsigned short f2bf(float f) {
    union { float f; uint32_t u; } v; v.f = f;
    uint32_t u = v.u;
    return (unsigned short)((u + 0x7FFFu + ((u >> 16) & 1u)) >> 16); // RNE
}

__device__ __forceinline__ float fast_exp2(float x) {
#if __has_builtin(__builtin_amdgcn_exp2f)
    return __builtin_amdgcn_exp2f(x);
#else
    return __expf(x * 0.6931471805599453f);
#endif
}
__device__ __forceinline__ float fast_rcp(float x) {
#if __has_builtin(__builtin_amdgcn_rcpf)
    return __builtin_amdgcn_rcpf(x);
#else
    return 1.f / x;
#endif
}
__device__ __forceinline__ float sigmoid_fast(float x) {
    return fast_rcp(1.f + fast_exp2(-LOG2E * x));
}
__device__ __forceinline__ float tanh_fast(float x) {
    return fmaf(-2.f, fast_rcp(1.f + fast_exp2((2.f * LOG2E) * x)), 1.f);
}

// In-chunk per-step barrier: LDS ordering only (lgkmcnt). Global prefetch
// loads and producer h-stores stay in flight across it. Full __syncthreads
// (vmcnt drain) only at chunk boundaries.
__device__ __forceinline__ void light_barrier() {
    asm volatile("s_waitcnt lgkmcnt(0)\n\ts_barrier" ::: "memory");
}

// ---------------- x fp32 -> bf16 convert (+ flag zeroing) ----------------
__global__ void conv_x_kernel(const float* __restrict__ x,
                              unsigned short* __restrict__ xb, int n4,
                              int* __restrict__ flags) {
    int i = blockIdx.x * blockDim.x + threadIdx.x;
    if (blockIdx.x == 0 && threadIdx.x < NTILE) flags[threadIdx.x] = 0;
    if (i >= n4) return;
    float4 f = ((const float4*)x)[i];
    ushort4 o;
    o.x = f2bf(f.x); o.y = f2bf(f.y); o.z = f2bf(f.z); o.w = f2bf(f.w);
    ((ushort4*)xb)[i] = o;
}

// ---------------- fused 2-layer pipelined LSTM + head ----------------
// 128 blocks x 512 threads. Blocks 0..63: layer0 (producer), 64..127: layer1
// (consumer), paired on batch tile bt. RB=4 batch rows at MFMA C-rows
// {0,4,8,12} -> every lane does exactly one cell update. x-projection MFMAs
// for step t+1 issue BEFORE the step barrier (independent of h(t)),
// overlapping the activation chain; post-barrier critical path is
// ds_read h -> 4 dependent h-MFMAs -> extract -> activation -> ds_write.
// CRITICAL (R5 lesson): every per-thread register array (xf0/xf1, accA/accB)
// is indexed ONLY with compile-time constants — the step loop is unrolled by
// 2 with statically-named double buffers. R5 used xf[t&1][kt] under
// #pragma unroll 1; the dynamic index demoted xf to scratch (private global
// memory) and put ~2 scratch round-trips on the serial path per step -> 65x
// regression. LDS (hbuf[cur]) may be dynamically indexed; VGPR arrays not.
template<int KIN, bool IS_PROD>
__device__ __forceinline__ void lstm_body(
    const unsigned short* __restrict__ xin,  // [BATCH][SEQ][KIN] bf16
    const float* __restrict__ Wih,           // [4H][KIN]
    const float* __restrict__ Whh,           // [4H][H]
    const float* __restrict__ b_ih, const float* __restrict__ b_hh,
    unsigned short* __restrict__ outseq,     // producer: [BATCH][SEQ][H] bf16
    const float* __restrict__ W1, const float* __restrict__ b1,
    const float* __restrict__ W2, const float* __restrict__ b2,
    float* __restrict__ out,                 // consumer: [BATCH][3]
    int* flag, int bt)
{
    constexpr int KT  = KIN / 32;
    constexpr int PAD = 132;                 // 66 dwords == 2 mod 32 -> 2-way (free) aliasing
    const int lane = threadIdx.x & 63;
    const int quad = lane >> 4;
    const int l16  = lane & 15;
    const int b0   = bt * RB;
    const int cell = (threadIdx.x >> 6) * 16 + l16;
    const int arow = l16 & 12;               // LDS h row this lane reads (4-lane broadcast)
    const int xrow = b0 + (l16 >> 2);        // batch row this lane loads (duplicated 4x)

    __shared__ short hbuf[2][16][PAD];
    __shared__ float hl[RB][128];            // fp32 h_last (consumer head input)
    __shared__ float mid[RB][65];
    for (int i = threadIdx.x; i < 2 * 16 * PAD; i += 512) ((short*)hbuf)[i] = 0;

    // ---- weight fragments (loaded once, fp32->bf16, persist in registers) ----
    short8 whh_f[4][4];
    short8 wih_f[4][KT];
    float  bias[4];
#pragma unroll
    for (int tT = 0; tT < 4; tT++) {
        const int n = tT * 128 + cell;
#pragma unroll
        for (int kt = 0; kt < 4; kt++) {
            const float* p = Whh + (size_t)n * H + kt * 32 + quad * 8;
            float4 f0 = *(const float4*)p;
            float4 f1 = *(const float4*)(p + 4);
            short8 s;
            s[0]=f2bf(f0.x); s[1]=f2bf(f0.y); s[2]=f2bf(f0.z); s[3]=f2bf(f0.w);
            s[4]=f2bf(f1.x); s[5]=f2bf(f1.y); s[6]=f2bf(f1.z); s[7]=f2bf(f1.w);
            whh_f[tT][kt] = s;
        }
#pragma unroll
        for (int kt = 0; kt < KT; kt++) {
            const float* p = Wih + (size_t)n * KIN + kt * 32 + quad * 8;
            float4 f0 = *(const float4*)p;
            float4 f1 = *(const float4*)(p + 4);
            short8 s;
            s[0]=f2bf(f0.x); s[1]=f2bf(f0.y); s[2]=f2bf(f0.z); s[3]=f2bf(f0.w);
            s[4]=f2bf(f1.x); s[5]=f2bf(f1.y); s[6]=f2bf(f1.z); s[7]=f2bf(f1.w);
            wih_f[tT][kt] = s;
        }
        bias[tT] = b_ih[n] + b_hh[n];
    }

    float c0 = 0.f;                          // this lane's single cell state

    const unsigned short* xp = xin + ((size_t)xrow * SEQ) * KIN + quad * 8;
    unsigned short* op = nullptr;
    if (IS_PROD)
        op = outseq + ((size_t)(b0 + quad) * SEQ) * H + cell;

    short8  xf0[KT], xf1[KT];                // statically-named x double buffer
    float4v accA[4], accB[4];                // statically-named acc double buffer
    __syncthreads();                         // hbuf zero-init visible

    // One pipelined half-step. CUR is compile-time; accUse carries
    // bias + x(t)-partial; computes accNext = bias + x-partial from xNext;
    // prefetches x(t+2) into xPre. All reg arrays bound statically by ref.
    auto halfstep = [&](int t, int CUR,
                        float4v (&accUse)[4], float4v (&accNext)[4],
                        short8 (&xPre)[KT], short8 (&xNext)[KT],
                        bool doPre, bool doNext) __attribute__((always_inline)) {
        short8 ha[4];
#pragma unroll
        for (int kt = 0; kt < 4; kt++)
            ha[kt] = *(const short8*)&hbuf[CUR][arow][kt * 32 + quad * 8];
#pragma unroll
        for (int tT = 0; tT < 4; tT++)
#pragma unroll
            for (int kt = 0; kt < 4; kt++)
                accUse[tT] = __builtin_amdgcn_mfma_f32_16x16x32_bf16(ha[kt], whh_f[tT][kt], accUse[tT], 0, 0, 0);
        float g0 = accUse[0][0], g1 = accUse[1][0], g2 = accUse[2][0], g3 = accUse[3][0];

        if (doPre) {
            const unsigned short* p = xp + (size_t)(t + 2) * KIN;
#pragma unroll
            for (int kt = 0; kt < KT; kt++) xPre[kt] = *(const short8*)(p + kt * 32);
        }
        if (doNext) {
#pragma unroll
            for (int tT = 0; tT < 4; tT++)
                accNext[tT] = (float4v){bias[tT], bias[tT], bias[tT], bias[tT]};
#pragma unroll
            for (int tT = 0; tT < 4; tT++)
#pragma unroll
                for (int kt = 0; kt < KT; kt++)
                    accNext[tT] = __builtin_amdgcn_mfma_f32_16x16x32_bf16(xNext[kt], wih_f[tT][kt], accNext[tT], 0, 0, 0);
        }

        float si = sigmoid_fast(g0);
        float sf = sigmoid_fast(g1);
        float tg = tanh_fast(g2);
        float so = sigmoid_fast(g3);
        float cn = fmaf(sf, c0, si * tg);
        c0 = cn;
        float h = so * tanh_fast(cn);
        const unsigned short hb = f2bf(h);
        hbuf[CUR ^ 1][quad * 4][cell] = (short)hb;
        if (IS_PROD) {
            *op = hb;                        // fire-and-forget; drained at chunk end
            op += H;
        } else if (t == SEQ - 1) {
            hl[quad][cell] = h;
        }
        light_barrier();                     // LDS-only: loads/stores stay in flight
    };

    for (int ch = 0; ch < NCH; ch++) {
        const int t0 = ch * CH;
        if (!IS_PROD) {
            if (threadIdx.x == 0) {
                while (__hip_atomic_load(flag, __ATOMIC_RELAXED, __HIP_MEMORY_SCOPE_AGENT) <= ch)
                    __builtin_amdgcn_s_sleep(2);
                (void)__hip_atomic_load(flag, __ATOMIC_ACQUIRE, __HIP_MEMORY_SCOPE_AGENT);
            }
            __syncthreads();
        }
        // chunk fill: consumer every chunk (x not available across the flag);
        // producer only once (its acc/prefetch pipeline runs across chunks)
        if (!IS_PROD || ch == 0) {
            const unsigned short* p0 = xp + (size_t)t0 * KIN;
            const unsigned short* p1 = p0 + KIN;
#pragma unroll
            for (int kt = 0; kt < KT; kt++) {
                xf0[kt] = *(const short8*)(p0 + kt * 32);
                xf1[kt] = *(const short8*)(p1 + kt * 32);
            }
#pragma unroll
            for (int tT = 0; tT < 4; tT++)
                accA[tT] = (float4v){bias[tT], bias[tT], bias[tT], bias[tT]};
#pragma unroll
            for (int tT = 0; tT < 4; tT++)
#pragma unroll
                for (int kt = 0; kt < KT; kt++)
                    accA[tT] = __builtin_amdgcn_mfma_f32_16x16x32_bf16(xf0[kt], wih_f[tT][kt], accA[tT], 0, 0, 0);
        }

#pragma unroll 1
        for (int i = 0; i < CH; i += 2) {
            const int t = t0 + i;
            const bool preA  = IS_PROD ? (t + 2 < SEQ) : (i + 2 < CH);
            const bool preB  = IS_PROD ? (t + 3 < SEQ) : (i + 3 < CH);
            const bool nextA = IS_PROD ? (t + 2 < SEQ) : (i + 2 < CH);
            // step A (t, even -> hbuf[0]): uses accA; computes accB for t+1
            halfstep(t,     0, accA, accB, xf0, xf1, preA, true);
            // step B (t+1 -> hbuf[1]): uses accB; computes accA for t+2
            halfstep(t + 1, 1, accB, accA, xf1, xf0, preB, nextA);
        }
        __syncthreads();                     // vmcnt drain (producer stores) + boundary
        if (IS_PROD && threadIdx.x == 0)
            __hip_atomic_fetch_add(flag, 1, __ATOMIC_RELEASE, __HIP_MEMORY_SCOPE_AGENT);
    }

    if (!IS_PROD) {
        // ---- MLP head for this block's RB rows (hl visible via last barrier)
        if (threadIdx.x < RB * 64) {
            const int row = threadIdx.x >> 6, j = threadIdx.x & 63;
            float s = b1[j];
            const float* wr = W1 + (size_t)j * 128;
#pragma unroll 8
            for (int k = 0; k < 128; k++) s = fmaf(hl[row][k], wr[k], s);
            mid[row][j] = fmaxf(s, 0.f);
        }
        __syncthreads();
        if (threadIdx.x < RB * 3) {
            const int row = threadIdx.x / 3, k = threadIdx.x - row * 3;
            float o = b2[k];
            const float* wr = W2 + (size_t)k * 64;
#pragma unroll 8
            for (int j = 0; j < 64; j++) o = fmaf(mid[row][j], wr[j], o);
            out[(size_t)(b0 + row) * 3 + k] = o;
        }
    }
}

__global__ __launch_bounds__(512, 2)
void lstm_fused_kernel(const unsigned short* __restrict__ xb,
                       const float* __restrict__ Wih0, const float* __restrict__ Whh0,
                       const float* __restrict__ bih0, const float* __restrict__ bhh0,
                       const float* __restrict__ Wih1, const float* __restrict__ Whh1,
                       const float* __restrict__ bih1, const float* __restrict__ bhh1,
                       unsigned short* __restrict__ h0sq,
                       const float* __restrict__ W1, const float* __restrict__ b1,
                       const float* __restrict__ W2, const float* __restrict__ b2,
                       float* __restrict__ out,
                       int* __restrict__ flags)
{
    const int bt = blockIdx.x & (NTILE - 1);
    if (blockIdx.x < NTILE)
        lstm_body<64,  true >(xb,   Wih0, Whh0, bih0, bhh0, h0sq,
                              W1, b1, W2, b2, out, flags + bt, bt);
    else
        lstm_body<128, false>(h0sq, Wih1, Whh1, bih1, bhh1, nullptr,
                              W1, b1, W2, b2, out, flags + bt, bt);
}

extern "C" void kernel_launch(void* const* d_in, const int* in_sizes, int n_in,
                              void* d_out, int out_size, void* d_ws, size_t ws_size,
                              hipStream_t stream) {
    const float* x     = (const float*)d_in[0];
    const float* W_ih0 = (const float*)d_in[1];
    const float* W_hh0 = (const float*)d_in[2];
    const float* b_ih0 = (const float*)d_in[3];
    const float* b_hh0 = (const float*)d_in[4];
    const float* W_ih1 = (const float*)d_in[5];
    const float* W_hh1 = (const float*)d_in[6];
    const float* b_ih1 = (const float*)d_in[7];
    const float* b_hh1 = (const float*)d_in[8];
    const float* W1    = (const float*)d_in[9];
    const float* b1    = (const float*)d_in[10];
    const float* W2    = (const float*)d_in[11];
    const float* b2    = (const float*)d_in[12];
    float* out = (float*)d_out;

    // workspace: xb bf16[256*512*64] @0 (16 MB); h0sq bf16[256*512*128] @16 MB (32 MB); flags @48 MB
    char* ws = (char*)d_ws;
    unsigned short* xb    = (unsigned short*)ws;
    unsigned short* h0sq  = (unsigned short*)(ws + 16777216);
    int*            flags = (int*)(ws + 50331648);

    conv_x_kernel<<<8192, 256, 0, stream>>>(x, xb, (BATCH * SEQ * INDIM) / 4, flags);
    lstm_fused_kernel<<<2 * NTILE, 512, 0, stream>>>(xb, W_ih0, W_hh0, b_ih0, b_hh0,
                                                     W_ih1, W_hh1, b_ih1, b_hh1,
                                                     h0sq, W1, b1, W2, b2, out, flags);
}